// Round 1
// baseline (998.935 us; speedup 1.0000x reference)
//
#include <hip/hip_runtime.h>

#ifndef NEG_SLOPE
#define NEG_SLOPE 0.2f
#endif

// ---------------------------------------------------------------------------
// Fused small GEMM: out[N,M] = x[N,64] @ W[64,M] (+bias) (+relu)
// Optionally computes alpha_s/alpha_d = (out * a_src/a_dst).sum(-1) via a
// 64-lane wave reduction (only valid for M==64, where one wave == one row).
// ---------------------------------------------------------------------------
template <int M, bool RELU, bool WANT_ALPHA>
__global__ __launch_bounds__(256) void gemm_small(
    const float* __restrict__ x, const float* __restrict__ W,
    const float* __restrict__ bias,
    const float* __restrict__ a_src, const float* __restrict__ a_dst,
    float* __restrict__ out, float* __restrict__ alpha_s,
    float* __restrict__ alpha_d, int N)
{
    constexpr int RPB = 256 / M;  // rows per block
    __shared__ float Ws[64 * M];
    __shared__ float Xs[RPB][64];

    for (int i = threadIdx.x; i < 64 * M; i += 256) Ws[i] = W[i];
    const int row0 = blockIdx.x * RPB;
    for (int i = threadIdx.x; i < RPB * 64; i += 256) {
        int r = i >> 6, c = i & 63;
        Xs[r][c] = (row0 + r < N) ? x[(row0 + r) * 64 + c] : 0.f;
    }
    __syncthreads();

    const int col = threadIdx.x % M;
    const int lr  = threadIdx.x / M;
    const int row = row0 + lr;

    float acc = 0.f;
#pragma unroll
    for (int k = 0; k < 64; ++k) acc += Xs[lr][k] * Ws[k * M + col];
    if (bias) acc += bias[col];
    if (RELU) acc = fmaxf(acc, 0.f);
    if (row < N) out[row * M + col] = acc;

    if (WANT_ALPHA) {
        // M==64: wave == row. Reduce h*a over the 64 lanes.
        float s = acc * a_src[col];
        float d = acc * a_dst[col];
#pragma unroll
        for (int off = 32; off > 0; off >>= 1) {
            s += __shfl_xor(s, off, 64);
            d += __shfl_xor(d, off, 64);
        }
        if (col == 0 && row < N) { alpha_s[row] = s; alpha_d[row] = d; }
    }
}

// ---------------------------------------------------------------------------
// Per-edge: e = leaky_relu(alpha_s[src] + alpha_d[dst]); segment-max into
// mkeys[dst] using the order-preserving uint encoding of float.
// ---------------------------------------------------------------------------
__device__ __forceinline__ unsigned int f2key(float f) {
    unsigned int fi = __float_as_uint(f);
    return (fi & 0x80000000u) ? ~fi : (fi | 0x80000000u);
}
__device__ __forceinline__ float key2f(unsigned int k) {
    return __uint_as_float((k & 0x80000000u) ? (k & 0x7FFFFFFFu) : ~k);
}

__global__ __launch_bounds__(256) void edge_e_max(
    const int* __restrict__ ei, int E,
    const float* __restrict__ as, const float* __restrict__ ad,
    float* __restrict__ ebuf, unsigned int* __restrict__ mkeys)
{
    int e = blockIdx.x * 256 + threadIdx.x;
    if (e >= E) return;
    int s = ei[e];
    int d = ei[E + e];
    float v = as[s] + ad[d];
    v = (v >= 0.f) ? v : NEG_SLOPE * v;
    ebuf[e] = v;
    atomicMax(&mkeys[d], f2key(v));
}

// ---------------------------------------------------------------------------
// Wave-per-edge aggregation: w = exp(e - m[dst]);
//   denom[dst] += w;  agg[dst][lane] += w * h[src][lane]  (lane = dim 0..63)
// ---------------------------------------------------------------------------
__global__ __launch_bounds__(256) void edge_agg(
    const int* __restrict__ ei, int E,
    const float* __restrict__ ebuf, const unsigned int* __restrict__ mkeys,
    const float* __restrict__ h, float* __restrict__ agg,
    float* __restrict__ denom)
{
    const int lane = threadIdx.x & 63;
    const int wave = (blockIdx.x * blockDim.x + threadIdx.x) >> 6;
    const int nw   = (gridDim.x * blockDim.x) >> 6;
    for (int e = wave; e < E; e += nw) {
        int s = ei[e];
        int d = ei[E + e];
        float m = key2f(mkeys[d]);
        float w = __expf(ebuf[e] - m);
        if (lane == 0) atomicAdd(&denom[d], w);
        atomicAdd(&agg[d * 64 + lane], w * h[s * 64 + lane]);
    }
}

// ---------------------------------------------------------------------------
// Node epilogue: x_next = relu(agg/denom + b)   (in place on agg)
// ---------------------------------------------------------------------------
__global__ __launch_bounds__(256) void node_final(
    float* __restrict__ agg, const float* __restrict__ denom,
    const float* __restrict__ bias, int N)
{
    int i = blockIdx.x * 256 + threadIdx.x;
    if (i >= N * 64) return;
    int d = i & 63, n = i >> 6;
    float den = denom[n];
    float v = (den > 0.f) ? (agg[i] / den) : 0.f;
    agg[i] = fmaxf(v + bias[d], 0.f);
}

extern "C" void kernel_launch(void* const* d_in, const int* in_sizes, int n_in,
                              void* d_out, int out_size, void* d_ws, size_t ws_size,
                              hipStream_t stream)
{
    const float* x  = (const float*)d_in[0];
    const int*   ei = (const int*)d_in[1];
    const float* W[3]    = {(const float*)d_in[2], (const float*)d_in[6],  (const float*)d_in[10]};
    const float* asrc[3] = {(const float*)d_in[3], (const float*)d_in[7],  (const float*)d_in[11]};
    const float* adst[3] = {(const float*)d_in[4], (const float*)d_in[8],  (const float*)d_in[12]};
    const float* bia[3]  = {(const float*)d_in[5], (const float*)d_in[9],  (const float*)d_in[13]};
    const float* lin1W = (const float*)d_in[14];
    const float* lin1b = (const float*)d_in[15];
    const float* lin2W = (const float*)d_in[16];
    const float* lin2b = (const float*)d_in[17];

    const int N = in_sizes[0] / 64;
    const int E = in_sizes[1] / 2;

    float* X     = (float*)d_ws;        // N*64 — current activations / agg target
    float* H     = X + (size_t)N * 64;  // N*64 — h = x@W
    float* ebuf  = H + (size_t)N * 64;  // E
    float* denom = ebuf + E;            // N
    unsigned int* mkeys = (unsigned int*)(denom + N);  // N (contiguous w/ denom)
    float* AS = (float*)(mkeys + N);    // N
    float* AD = AS + N;                 // N

    // X <- input activations (inputs must stay unmutated)
    hipMemcpyAsync(X, x, (size_t)N * 64 * sizeof(float),
                   hipMemcpyDeviceToDevice, stream);

    const int gemm_grid64 = (N + 3) / 4;
    const int edge_grid   = (E + 255) / 256;
    const int node_grid   = (N * 64 + 255) / 256;

    for (int l = 0; l < 3; ++l) {
        // h = X @ W  (+ alpha_s, alpha_d)
        gemm_small<64, false, true><<<gemm_grid64, 256, 0, stream>>>(
            X, W[l], nullptr, asrc[l], adst[l], H, AS, AD, N);
        // zero agg (reuses X — dead after gemm) and denom+mkeys
        hipMemsetAsync(X, 0, (size_t)N * 64 * sizeof(float), stream);
        hipMemsetAsync(denom, 0, (size_t)2 * N * sizeof(float), stream);
        // e + segment max
        edge_e_max<<<edge_grid, 256, 0, stream>>>(ei, E, AS, AD, ebuf, mkeys);
        // softmax-weighted aggregation
        edge_agg<<<8192, 256, 0, stream>>>(ei, E, ebuf, mkeys, H, X, denom);
        // relu(agg/denom + b) -> next layer activations (in place on X)
        node_final<<<node_grid, 256, 0, stream>>>(X, denom, bia[l], N);
    }

    // MLP head: H = relu(X @ lin1_W + lin1_b); out = H @ lin2_W + lin2_b
    gemm_small<64, true, false><<<gemm_grid64, 256, 0, stream>>>(
        X, lin1W, lin1b, nullptr, nullptr, H, nullptr, nullptr, N);
    gemm_small<32, false, false><<<(N + 7) / 8, 256, 0, stream>>>(
        H, lin2W, lin2b, nullptr, nullptr, (float*)d_out, nullptr, nullptr, N);
}

// Round 2
// 383.787 us; speedup vs baseline: 2.6028x; 2.6028x over previous
//
#include <hip/hip_runtime.h>

#define NEG_SLOPE 0.2f
#define FLT_BIG 3.402823466e+38f

// ---------------------------------------------------------------------------
// Fused small GEMM: out[N,M] = x[N,64] @ W[64,M] (+bias) (+relu)
// Optionally computes alpha_s/alpha_d = (out * a_src/a_dst).sum(-1) via a
// 64-lane wave reduction (only valid for M==64, where one wave == one row).
// ---------------------------------------------------------------------------
template <int M, bool RELU, bool WANT_ALPHA>
__global__ __launch_bounds__(256) void gemm_small(
    const float* __restrict__ x, const float* __restrict__ W,
    const float* __restrict__ bias,
    const float* __restrict__ a_src, const float* __restrict__ a_dst,
    float* __restrict__ out, float* __restrict__ alpha_s,
    float* __restrict__ alpha_d, int N)
{
    constexpr int RPB = 256 / M;  // rows per block
    __shared__ float Ws[64 * M];
    __shared__ float Xs[RPB][64];

    for (int i = threadIdx.x; i < 64 * M; i += 256) Ws[i] = W[i];
    const int row0 = blockIdx.x * RPB;
    for (int i = threadIdx.x; i < RPB * 64; i += 256) {
        int r = i >> 6, c = i & 63;
        Xs[r][c] = (row0 + r < N) ? x[(size_t)(row0 + r) * 64 + c] : 0.f;
    }
    __syncthreads();

    const int col = threadIdx.x % M;
    const int lr  = threadIdx.x / M;
    const int row = row0 + lr;

    float acc = 0.f;
#pragma unroll
    for (int k = 0; k < 64; ++k) acc += Xs[lr][k] * Ws[k * M + col];
    if (bias) acc += bias[col];
    if (RELU) acc = fmaxf(acc, 0.f);
    if (row < N) out[(size_t)row * M + col] = acc;

    if (WANT_ALPHA) {
        float s = acc * a_src[col];
        float d = acc * a_dst[col];
#pragma unroll
        for (int off = 32; off > 0; off >>= 1) {
            s += __shfl_xor(s, off, 64);
            d += __shfl_xor(d, off, 64);
        }
        if (col == 0 && row < N) { alpha_s[row] = s; alpha_d[row] = d; }
    }
}

// ---------------------------------------------------------------------------
// CSR build: histogram(dst) -> exclusive scan -> scatter src by dst
// ---------------------------------------------------------------------------
__global__ __launch_bounds__(256) void hist_kernel(
    const int* __restrict__ ei, int E, int* __restrict__ counts)
{
    int e = blockIdx.x * 256 + threadIdx.x;
    if (e < E) atomicAdd(&counts[ei[E + e]], 1);
}

__global__ __launch_bounds__(256) void scan_block_sums(
    const int* __restrict__ counts, int N, int* __restrict__ bsums)
{
    __shared__ int sm[256];
    int i = blockIdx.x * 256 + threadIdx.x;
    sm[threadIdx.x] = (i < N) ? counts[i] : 0;
    __syncthreads();
    for (int off = 128; off > 0; off >>= 1) {
        if (threadIdx.x < off) sm[threadIdx.x] += sm[threadIdx.x + off];
        __syncthreads();
    }
    if (threadIdx.x == 0) bsums[blockIdx.x] = sm[0];
}

// single block: exclusive scan of nb (<=256) block sums
__global__ __launch_bounds__(256) void scan_top(
    const int* __restrict__ bsums, int nb, int* __restrict__ boffs)
{
    __shared__ int sm[256];
    int t = threadIdx.x;
    int v = (t < nb) ? bsums[t] : 0;
    sm[t] = v; __syncthreads();
    for (int off = 1; off < 256; off <<= 1) {
        int x = sm[t];
        if (t >= off) x += sm[t - off];
        __syncthreads(); sm[t] = x; __syncthreads();
    }
    if (t < nb) boffs[t] = sm[t] - v;
}

// in-place: counts[i] -> row_off[i] (exclusive); also fill cursor copy
__global__ __launch_bounds__(256) void scan_final(
    int* __restrict__ counts, int N, int E,
    const int* __restrict__ boffs, int* __restrict__ cursor)
{
    __shared__ int sm[256];
    int t = threadIdx.x;
    int i = blockIdx.x * 256 + t;
    int v = (i < N) ? counts[i] : 0;
    sm[t] = v; __syncthreads();
    for (int off = 1; off < 256; off <<= 1) {
        int x = sm[t];
        if (t >= off) x += sm[t - off];
        __syncthreads(); sm[t] = x; __syncthreads();
    }
    if (i < N) {
        int excl = boffs[blockIdx.x] + sm[t] - v;
        counts[i] = excl;
        cursor[i] = excl;
    }
    if (i == 0) counts[N] = E;
}

__global__ __launch_bounds__(256) void scatter_kernel(
    const int* __restrict__ ei, int E,
    int* __restrict__ cursor, int* __restrict__ csr_src)
{
    int e = blockIdx.x * 256 + threadIdx.x;
    if (e < E) {
        int s = ei[e], d = ei[E + e];
        int pos = atomicAdd(&cursor[d], 1);
        csr_src[pos] = s;
    }
}

// ---------------------------------------------------------------------------
// GAT aggregation, one wave per dst node. 4 edge-groups x 16 lanes; each lane
// holds float4 of the 64-dim accumulator. Online softmax in registers.
// out[d] = relu( (sum_e w_e * h[src_e]) / (sum_e w_e) + bias )
// ---------------------------------------------------------------------------
__global__ __launch_bounds__(256) void gat_aggregate(
    const int* __restrict__ row_off, const int* __restrict__ csr_src,
    const float* __restrict__ h, const float* __restrict__ as,
    const float* __restrict__ ad, const float* __restrict__ bias,
    float* __restrict__ out, int N)
{
    const int wave = (blockIdx.x * 256 + threadIdx.x) >> 6;
    if (wave >= N) return;
    const int d    = wave;
    const int lane = threadIdx.x & 63;
    const int g    = lane >> 4;   // edge group 0..3
    const int gl   = lane & 15;   // lane in group -> dims [gl*4, gl*4+4)

    const int beg = row_off[d], end = row_off[d + 1];
    const float add = ad[d];

    float  m   = -FLT_BIG;
    float  den = 0.f;
    float4 acc = {0.f, 0.f, 0.f, 0.f};

    for (int e0 = beg; e0 < end; e0 += 4) {
        const int  e     = e0 + g;
        const bool valid = (e < end);
        const int  src   = valid ? csr_src[e] : 0;

        float ev = -FLT_BIG;
        if (valid) {
            float v = as[src] + add;
            ev = (v >= 0.f) ? v : NEG_SLOPE * v;
        }
        // chunk max across the 4 groups (wave-uniform)
        float cm = ev;
        cm = fmaxf(cm, __shfl_xor(cm, 16, 64));
        cm = fmaxf(cm, __shfl_xor(cm, 32, 64));
        const float nm = fmaxf(m, cm);           // finite (g==0 always valid)
        const float scale = __expf(m - nm);      // 1 if unchanged, 0 on first
        acc.x *= scale; acc.y *= scale; acc.z *= scale; acc.w *= scale;
        den   *= scale;
        m = nm;

        const float w = valid ? __expf(ev - m) : 0.f;
        den += w;
        if (valid) {
            const float4 hv = *(const float4*)&h[(size_t)src * 64 + gl * 4];
            acc.x += w * hv.x; acc.y += w * hv.y;
            acc.z += w * hv.z; acc.w += w * hv.w;
        }
    }

    // reduce the 4 groups (lanes differ in bits 4,5)
#pragma unroll
    for (int off = 16; off <= 32; off <<= 1) {
        acc.x += __shfl_xor(acc.x, off, 64);
        acc.y += __shfl_xor(acc.y, off, 64);
        acc.z += __shfl_xor(acc.z, off, 64);
        acc.w += __shfl_xor(acc.w, off, 64);
        den   += __shfl_xor(den,   off, 64);
    }

    if (g == 0) {
        const float4 bv = *(const float4*)&bias[gl * 4];
        const float inv = (den > 0.f) ? (1.f / den) : 0.f;
        float4 o;
        o.x = fmaxf(acc.x * inv + bv.x, 0.f);
        o.y = fmaxf(acc.y * inv + bv.y, 0.f);
        o.z = fmaxf(acc.z * inv + bv.z, 0.f);
        o.w = fmaxf(acc.w * inv + bv.w, 0.f);
        *(float4*)&out[(size_t)d * 64 + gl * 4] = o;
    }
}

extern "C" void kernel_launch(void* const* d_in, const int* in_sizes, int n_in,
                              void* d_out, int out_size, void* d_ws, size_t ws_size,
                              hipStream_t stream)
{
    const float* x  = (const float*)d_in[0];
    const int*   ei = (const int*)d_in[1];
    const float* W[3]    = {(const float*)d_in[2], (const float*)d_in[6],  (const float*)d_in[10]};
    const float* asrc[3] = {(const float*)d_in[3], (const float*)d_in[7],  (const float*)d_in[11]};
    const float* adst[3] = {(const float*)d_in[4], (const float*)d_in[8],  (const float*)d_in[12]};
    const float* bia[3]  = {(const float*)d_in[5], (const float*)d_in[9],  (const float*)d_in[13]};
    const float* lin1W = (const float*)d_in[14];
    const float* lin1b = (const float*)d_in[15];
    const float* lin2W = (const float*)d_in[16];
    const float* lin2b = (const float*)d_in[17];

    const int N = in_sizes[0] / 64;
    const int E = in_sizes[1] / 2;

    // workspace layout
    float* X       = (float*)d_ws;              // N*64
    float* H       = X + (size_t)N * 64;        // N*64
    float* AS      = H + (size_t)N * 64;        // N
    float* AD      = AS + N;                    // N
    int*   row_off = (int*)(AD + N);            // N+1 (counts in-place -> row_off)
    int*   cursor  = row_off + (N + 1);         // N
    int*   csr_src = cursor + N;                // E
    int*   bsums   = csr_src + E;               // 256
    int*   boffs   = bsums + 256;               // 256

    const int nb        = (N + 255) / 256;      // scan blocks (<=256 required)
    const int edge_grid = (E + 255) / 256;
    const int gemm_grid = (N + 3) / 4;          // RPB=4 for M=64
    const int agg_grid  = (N + 3) / 4;          // 4 waves/block

    // ---- CSR build (per call; edge_index is an input) ----
    hipMemsetAsync(row_off, 0, (size_t)(N + 1) * sizeof(int), stream);
    hist_kernel<<<edge_grid, 256, 0, stream>>>(ei, E, row_off);
    scan_block_sums<<<nb, 256, 0, stream>>>(row_off, N, bsums);
    scan_top<<<1, 256, 0, stream>>>(bsums, nb, boffs);
    scan_final<<<nb, 256, 0, stream>>>(row_off, N, E, boffs, cursor);
    scatter_kernel<<<edge_grid, 256, 0, stream>>>(ei, E, cursor, csr_src);

    // ---- 3 GAT layers ----
    for (int l = 0; l < 3; ++l) {
        const float* in_act = (l == 0) ? x : X;
        gemm_small<64, false, true><<<gemm_grid, 256, 0, stream>>>(
            in_act, W[l], nullptr, asrc[l], adst[l], H, AS, AD, N);
        gat_aggregate<<<agg_grid, 256, 0, stream>>>(
            row_off, csr_src, H, AS, AD, bia[l], X, N);
    }

    // ---- MLP head ----
    gemm_small<64, true, false><<<gemm_grid, 256, 0, stream>>>(
        X, lin1W, lin1b, nullptr, nullptr, H, nullptr, nullptr, N);
    gemm_small<32, false, false><<<(N + 7) / 8, 256, 0, stream>>>(
        H, lin2W, lin2b, nullptr, nullptr, (float*)d_out, nullptr, nullptr, N);
}

// Round 3
// 282.319 us; speedup vs baseline: 3.5383x; 1.3594x over previous
//
#include <hip/hip_runtime.h>

#define NEG_SLOPE 0.2f
#define FLT_BIG 3.402823466e+38f

// ===========================================================================
// Register-blocked GEMM: out[N,64] = x[N,64] @ W[64,64] (+bias) (+relu)
// 64 rows x 64 cols per block; 256 threads; each thread computes 4x4 outputs.
// Optionally produces alpha_s/alpha_d = (out * a).sum(-1) via 16-lane reduce.
// ===========================================================================
template <bool RELU, bool WANT_ALPHA>
__global__ __launch_bounds__(256) void gemm64(
    const float* __restrict__ x, const float* __restrict__ W,
    const float* __restrict__ bias,
    const float* __restrict__ a_src, const float* __restrict__ a_dst,
    float* __restrict__ out, float* __restrict__ alpha_s,
    float* __restrict__ alpha_d, int N)
{
    __shared__ float Xs[64][68];   // +4 pad: Xs col-reads become 2-way max
    __shared__ float Ws[64][64];

    const int row0 = blockIdx.x * 64;

    for (int i = threadIdx.x; i < 1024; i += 256)
        ((float4*)Ws)[i] = ((const float4*)W)[i];
    for (int i = threadIdx.x; i < 1024; i += 256) {
        int r = i >> 4, c4 = (i & 15) * 4;
        float4 v = {0.f, 0.f, 0.f, 0.f};
        if (row0 + r < N) v = *(const float4*)&x[(size_t)(row0 + r) * 64 + c4];
        *(float4*)&Xs[r][c4] = v;
    }
    __syncthreads();

    const int tx = threadIdx.x & 15;   // col group: cols 4*tx..4*tx+3
    const int ty = threadIdx.x >> 4;   // row group: rows 4*ty..4*ty+3

    float acc[4][4] = {{0.f,0.f,0.f,0.f},{0.f,0.f,0.f,0.f},
                       {0.f,0.f,0.f,0.f},{0.f,0.f,0.f,0.f}};

#pragma unroll 8
    for (int k = 0; k < 64; ++k) {
        const float4 wv = *(const float4*)&Ws[k][tx * 4];
        const float x0 = Xs[ty * 4 + 0][k];
        const float x1 = Xs[ty * 4 + 1][k];
        const float x2 = Xs[ty * 4 + 2][k];
        const float x3 = Xs[ty * 4 + 3][k];
        acc[0][0] += x0 * wv.x; acc[0][1] += x0 * wv.y;
        acc[0][2] += x0 * wv.z; acc[0][3] += x0 * wv.w;
        acc[1][0] += x1 * wv.x; acc[1][1] += x1 * wv.y;
        acc[1][2] += x1 * wv.z; acc[1][3] += x1 * wv.w;
        acc[2][0] += x2 * wv.x; acc[2][1] += x2 * wv.y;
        acc[2][2] += x2 * wv.z; acc[2][3] += x2 * wv.w;
        acc[3][0] += x3 * wv.x; acc[3][1] += x3 * wv.y;
        acc[3][2] += x3 * wv.z; acc[3][3] += x3 * wv.w;
    }

    float4 bv = {0.f, 0.f, 0.f, 0.f};
    if (bias) bv = *(const float4*)&bias[tx * 4];

#pragma unroll
    for (int i = 0; i < 4; ++i) {
        const int r = row0 + ty * 4 + i;
        if (r < N) {
            float4 o;
            o.x = acc[i][0] + bv.x; o.y = acc[i][1] + bv.y;
            o.z = acc[i][2] + bv.z; o.w = acc[i][3] + bv.w;
            if (RELU) {
                o.x = fmaxf(o.x, 0.f); o.y = fmaxf(o.y, 0.f);
                o.z = fmaxf(o.z, 0.f); o.w = fmaxf(o.w, 0.f);
            }
            *(float4*)&out[(size_t)r * 64 + tx * 4] = o;
        }
    }

    if (WANT_ALPHA) {
        const float4 asv = *(const float4*)&a_src[tx * 4];
        const float4 adv = *(const float4*)&a_dst[tx * 4];
#pragma unroll
        for (int i = 0; i < 4; ++i) {
            float s = acc[i][0]*asv.x + acc[i][1]*asv.y
                    + acc[i][2]*asv.z + acc[i][3]*asv.w;
            float d = acc[i][0]*adv.x + acc[i][1]*adv.y
                    + acc[i][2]*adv.z + acc[i][3]*adv.w;
#pragma unroll
            for (int off = 1; off < 16; off <<= 1) {
                s += __shfl_xor(s, off, 16);
                d += __shfl_xor(d, off, 16);
            }
            const int r = row0 + ty * 4 + i;
            if (tx == 0 && r < N) { alpha_s[r] = s; alpha_d[r] = d; }
        }
    }
}

// ---------------------------------------------------------------------------
// Legacy small GEMM, kept for the final [N,64]x[64,32] projection.
// ---------------------------------------------------------------------------
template <int M>
__global__ __launch_bounds__(256) void gemm_small(
    const float* __restrict__ x, const float* __restrict__ W,
    const float* __restrict__ bias, float* __restrict__ out, int N)
{
    constexpr int RPB = 256 / M;
    __shared__ float Ws[64 * M];
    __shared__ float Xs[RPB][64];

    for (int i = threadIdx.x; i < 64 * M; i += 256) Ws[i] = W[i];
    const int row0 = blockIdx.x * RPB;
    for (int i = threadIdx.x; i < RPB * 64; i += 256) {
        int r = i >> 6, c = i & 63;
        Xs[r][c] = (row0 + r < N) ? x[(size_t)(row0 + r) * 64 + c] : 0.f;
    }
    __syncthreads();

    const int col = threadIdx.x % M;
    const int lr  = threadIdx.x / M;
    const int row = row0 + lr;

    float acc = 0.f;
#pragma unroll
    for (int k = 0; k < 64; ++k) acc += Xs[lr][k] * Ws[k * M + col];
    acc += bias[col];
    if (row < N) out[(size_t)row * M + col] = acc;
}

// ===========================================================================
// CSR build: hist -> scan -> coarse bucket partition -> in-bucket scatter
// ===========================================================================
__global__ __launch_bounds__(256) void hist_kernel(
    const int* __restrict__ ei, int E, int* __restrict__ counts)
{
    int e = blockIdx.x * 256 + threadIdx.x;
    if (e < E) atomicAdd(&counts[ei[E + e]], 1);
}

__global__ __launch_bounds__(256) void scan_block_sums(
    const int* __restrict__ counts, int N, int* __restrict__ bsums)
{
    __shared__ int sm[256];
    int i = blockIdx.x * 256 + threadIdx.x;
    sm[threadIdx.x] = (i < N) ? counts[i] : 0;
    __syncthreads();
    for (int off = 128; off > 0; off >>= 1) {
        if (threadIdx.x < off) sm[threadIdx.x] += sm[threadIdx.x + off];
        __syncthreads();
    }
    if (threadIdx.x == 0) bsums[blockIdx.x] = sm[0];
}

__global__ __launch_bounds__(256) void scan_top(
    const int* __restrict__ bsums, int nb, int* __restrict__ boffs)
{
    __shared__ int sm[256];
    int t = threadIdx.x;
    int v = (t < nb) ? bsums[t] : 0;
    sm[t] = v; __syncthreads();
    for (int off = 1; off < 256; off <<= 1) {
        int x = sm[t];
        if (t >= off) x += sm[t - off];
        __syncthreads(); sm[t] = x; __syncthreads();
    }
    if (t < nb) boffs[t] = sm[t] - v;
}

__global__ __launch_bounds__(256) void scan_final(
    int* __restrict__ counts, int N, int E, const int* __restrict__ boffs)
{
    __shared__ int sm[256];
    int t = threadIdx.x;
    int i = blockIdx.x * 256 + t;
    int v = (i < N) ? counts[i] : 0;
    sm[t] = v; __syncthreads();
    for (int off = 1; off < 256; off <<= 1) {
        int x = sm[t];
        if (t >= off) x += sm[t - off];
        __syncthreads(); sm[t] = x; __syncthreads();
    }
    if (i < N) counts[i] = boffs[blockIdx.x] + sm[t] - v;
    if (i == 0) counts[N] = E;
}

// gcurs[b] = start offset of bucket b (nodes [256b, 256b+256))
__global__ __launch_bounds__(256) void cursors_init(
    const int* __restrict__ row_off, int N, int B, int* __restrict__ gcurs)
{
    int b = blockIdx.x * 256 + threadIdx.x;
    if (b < B) gcurs[b] = row_off[min(b * 256, N)];
}

// Pass A: bin edges into 256-node buckets; packed record = src | (ln<<16)
#define PC_EPT 8
#define PC_TILE 2048
__global__ __launch_bounds__(256) void partition_coarse(
    const int* __restrict__ ei, int E,
    int* __restrict__ gcurs, int* __restrict__ pairs)
{
    __shared__ int hist[256];
    __shared__ int base[256];
    const int t = threadIdx.x;
    hist[t] = 0;
    __syncthreads();

    const int tile0 = blockIdx.x * PC_TILE;
    int sv[PC_EPT], dv[PC_EPT], rk[PC_EPT];
#pragma unroll
    for (int i = 0; i < PC_EPT; ++i) {
        const int e = tile0 + i * 256 + t;
        if (e < E) {
            sv[i] = ei[e];
            dv[i] = ei[E + e];
            rk[i] = atomicAdd(&hist[dv[i] >> 8], 1);
        } else dv[i] = -1;
    }
    __syncthreads();
    if (hist[t] > 0) base[t] = atomicAdd(&gcurs[t], hist[t]);
    __syncthreads();
#pragma unroll
    for (int i = 0; i < PC_EPT; ++i) {
        if (dv[i] >= 0) {
            const int b = dv[i] >> 8;
            pairs[base[b] + rk[i]] = sv[i] | ((dv[i] & 255) << 16);
        }
    }
}

// Pass B: one block per bucket; scatter into final CSR via LDS node cursors.
__global__ __launch_bounds__(256) void fine_scatter(
    const int* __restrict__ row_off, const int* __restrict__ pairs,
    int N, int* __restrict__ csr_src)
{
    __shared__ int cur[256];
    const int n0 = blockIdx.x * 256;
    const int t  = threadIdx.x;
    const int nn = min(256, N - n0);
    if (t < nn) cur[t] = row_off[n0 + t];
    __syncthreads();
    const int beg = row_off[n0];
    const int end = row_off[min(n0 + 256, N)];
    for (int p = beg + t; p < end; p += 256) {
        const int v  = pairs[p];
        const int pos = atomicAdd(&cur[v >> 16], 1);
        csr_src[pos] = v & 0xFFFF;
    }
}

// ===========================================================================
// GAT aggregation, one wave per dst. 4 edge-groups x 16 lanes; float4 accum.
// Online softmax; next-chunk src/alpha prefetch pipelined.
// ===========================================================================
__global__ __launch_bounds__(256) void gat_aggregate(
    const int* __restrict__ row_off, const int* __restrict__ csr_src,
    const float* __restrict__ h, const float* __restrict__ as,
    const float* __restrict__ ad, const float* __restrict__ bias,
    float* __restrict__ out, int N)
{
    const int wave = (blockIdx.x * 256 + threadIdx.x) >> 6;
    if (wave >= N) return;
    const int d    = wave;
    const int lane = threadIdx.x & 63;
    const int g    = lane >> 4;
    const int gl   = lane & 15;

    const int beg = row_off[d], end = row_off[d + 1];
    const float add = ad[d];

    float  m   = -FLT_BIG;
    float  den = 0.f;
    float4 acc = {0.f, 0.f, 0.f, 0.f};

    // prefetch pipeline: src + alpha_src for the current chunk
    int   e    = beg + g;
    int   srcp = (e < end) ? csr_src[e] : 0;
    float avp  = as[srcp];

    for (int e0 = beg; e0 < end; e0 += 4) {
        const bool valid = (e0 + g < end);
        const int   src  = srcp;
        const float av   = avp;

        const int en = e0 + 4 + g;
        srcp = (en < end) ? csr_src[en] : 0;   // prefetch next chunk
        avp  = as[srcp];

        // issue the h gather early; consumed after the shuffle/exp chain
        float4 hv = {0.f, 0.f, 0.f, 0.f};
        if (valid) hv = *(const float4*)&h[(size_t)src * 64 + gl * 4];

        float ev = -FLT_BIG;
        if (valid) {
            const float v = av + add;
            ev = (v >= 0.f) ? v : NEG_SLOPE * v;
        }
        float cm = ev;
        cm = fmaxf(cm, __shfl_xor(cm, 16, 64));
        cm = fmaxf(cm, __shfl_xor(cm, 32, 64));
        const float nm    = fmaxf(m, cm);
        const float scale = __expf(m - nm);
        acc.x *= scale; acc.y *= scale; acc.z *= scale; acc.w *= scale;
        den   *= scale;
        m = nm;

        const float w = valid ? __expf(ev - m) : 0.f;
        den += w;
        acc.x += w * hv.x; acc.y += w * hv.y;
        acc.z += w * hv.z; acc.w += w * hv.w;
    }

#pragma unroll
    for (int off = 16; off <= 32; off <<= 1) {
        acc.x += __shfl_xor(acc.x, off, 64);
        acc.y += __shfl_xor(acc.y, off, 64);
        acc.z += __shfl_xor(acc.z, off, 64);
        acc.w += __shfl_xor(acc.w, off, 64);
        den   += __shfl_xor(den,   off, 64);
    }

    if (g == 0) {
        const float4 bvv = *(const float4*)&bias[gl * 4];
        const float inv = (den > 0.f) ? (1.f / den) : 0.f;
        float4 o;
        o.x = fmaxf(acc.x * inv + bvv.x, 0.f);
        o.y = fmaxf(acc.y * inv + bvv.y, 0.f);
        o.z = fmaxf(acc.z * inv + bvv.z, 0.f);
        o.w = fmaxf(acc.w * inv + bvv.w, 0.f);
        *(float4*)&out[(size_t)d * 64 + gl * 4] = o;
    }
}

extern "C" void kernel_launch(void* const* d_in, const int* in_sizes, int n_in,
                              void* d_out, int out_size, void* d_ws, size_t ws_size,
                              hipStream_t stream)
{
    const float* x  = (const float*)d_in[0];
    const int*   ei = (const int*)d_in[1];
    const float* W[3]    = {(const float*)d_in[2], (const float*)d_in[6],  (const float*)d_in[10]};
    const float* asrc[3] = {(const float*)d_in[3], (const float*)d_in[7],  (const float*)d_in[11]};
    const float* adst[3] = {(const float*)d_in[4], (const float*)d_in[8],  (const float*)d_in[12]};
    const float* bia[3]  = {(const float*)d_in[5], (const float*)d_in[9],  (const float*)d_in[13]};
    const float* lin1W = (const float*)d_in[14];
    const float* lin1b = (const float*)d_in[15];
    const float* lin2W = (const float*)d_in[16];
    const float* lin2b = (const float*)d_in[17];

    const int N = in_sizes[0] / 64;
    const int E = in_sizes[1] / 2;
    const int B = (N + 255) / 256;           // coarse buckets (196)

    // workspace layout
    float* X       = (float*)d_ws;           // N*64
    float* H       = X + (size_t)N * 64;     // N*64 (reused as pairs during CSR build)
    float* AS      = H + (size_t)N * 64;     // N
    float* AD      = AS + N;                 // N
    int*   row_off = (int*)(AD + N);         // N+1
    int*   csr_src = row_off + (N + 1);      // E
    int*   bsums   = csr_src + E;            // 256
    int*   boffs   = bsums + 256;            // 256
    int*   gcurs   = boffs + 256;            // 256
    int*   pairs   = (int*)H;                // E ints (H is dead until gemm)

    const int nb        = (N + 255) / 256;
    const int edge_grid = (E + 255) / 256;
    const int g64_grid  = (N + 63) / 64;
    const int agg_grid  = (N + 3) / 4;
    const int pc_grid   = (E + PC_TILE - 1) / PC_TILE;

    // ---- CSR build ----
    hipMemsetAsync(row_off, 0, (size_t)(N + 1) * sizeof(int), stream);
    hist_kernel<<<edge_grid, 256, 0, stream>>>(ei, E, row_off);
    scan_block_sums<<<nb, 256, 0, stream>>>(row_off, N, bsums);
    scan_top<<<1, 256, 0, stream>>>(bsums, nb, boffs);
    scan_final<<<nb, 256, 0, stream>>>(row_off, N, E, boffs);
    cursors_init<<<1, 256, 0, stream>>>(row_off, N, B, gcurs);
    partition_coarse<<<pc_grid, 256, 0, stream>>>(ei, E, gcurs, pairs);
    fine_scatter<<<B, 256, 0, stream>>>(row_off, pairs, N, csr_src);

    // ---- 3 GAT layers ----
    for (int l = 0; l < 3; ++l) {
        const float* in_act = (l == 0) ? x : X;
        gemm64<false, true><<<g64_grid, 256, 0, stream>>>(
            in_act, W[l], nullptr, asrc[l], adst[l], H, AS, AD, N);
        gat_aggregate<<<agg_grid, 256, 0, stream>>>(
            row_off, csr_src, H, AS, AD, bia[l], X, N);
    }

    // ---- MLP head ----
    gemm64<true, false><<<g64_grid, 256, 0, stream>>>(
        X, lin1W, lin1b, nullptr, nullptr, H, nullptr, nullptr, N);
    gemm_small<32><<<(N + 7) / 8, 256, 0, stream>>>(
        H, lin2W, lin2b, (float*)d_out, N);
}

// Round 4
// 244.182 us; speedup vs baseline: 4.0909x; 1.1562x over previous
//
#include <hip/hip_runtime.h>

#define NEG_SLOPE 0.2f
#define FLT_BIG 3.402823466e+38f
#define NBUCK 256

// ===========================================================================
// Register-blocked GEMM: out[N,64] = x[N,64] @ W[64,64] (+bias) (+relu)
// 64x64 tile per block; 256 threads; 4x4 outputs/thread.
// Optionally produces alpha_s/alpha_d = (out * a).sum(-1) via 16-lane reduce.
// ===========================================================================
template <bool RELU, bool WANT_ALPHA>
__global__ __launch_bounds__(256) void gemm64(
    const float* __restrict__ x, const float* __restrict__ W,
    const float* __restrict__ bias,
    const float* __restrict__ a_src, const float* __restrict__ a_dst,
    float* __restrict__ out, float* __restrict__ alpha_s,
    float* __restrict__ alpha_d, int N)
{
    __shared__ float Xs[64][68];   // +4 pad: column reads 2-way max (free)
    __shared__ float Ws[64][64];

    const int row0 = blockIdx.x * 64;

    for (int i = threadIdx.x; i < 1024; i += 256)
        ((float4*)Ws)[i] = ((const float4*)W)[i];
    for (int i = threadIdx.x; i < 1024; i += 256) {
        int r = i >> 4, c4 = (i & 15) * 4;
        float4 v = {0.f, 0.f, 0.f, 0.f};
        if (row0 + r < N) v = *(const float4*)&x[(size_t)(row0 + r) * 64 + c4];
        *(float4*)&Xs[r][c4] = v;
    }
    __syncthreads();

    const int tx = threadIdx.x & 15;
    const int ty = threadIdx.x >> 4;

    float acc[4][4] = {{0.f,0.f,0.f,0.f},{0.f,0.f,0.f,0.f},
                       {0.f,0.f,0.f,0.f},{0.f,0.f,0.f,0.f}};

#pragma unroll 8
    for (int k = 0; k < 64; ++k) {
        const float4 wv = *(const float4*)&Ws[k][tx * 4];
        const float x0 = Xs[ty * 4 + 0][k];
        const float x1 = Xs[ty * 4 + 1][k];
        const float x2 = Xs[ty * 4 + 2][k];
        const float x3 = Xs[ty * 4 + 3][k];
        acc[0][0] += x0 * wv.x; acc[0][1] += x0 * wv.y;
        acc[0][2] += x0 * wv.z; acc[0][3] += x0 * wv.w;
        acc[1][0] += x1 * wv.x; acc[1][1] += x1 * wv.y;
        acc[1][2] += x1 * wv.z; acc[1][3] += x1 * wv.w;
        acc[2][0] += x2 * wv.x; acc[2][1] += x2 * wv.y;
        acc[2][2] += x2 * wv.z; acc[2][3] += x2 * wv.w;
        acc[3][0] += x3 * wv.x; acc[3][1] += x3 * wv.y;
        acc[3][2] += x3 * wv.z; acc[3][3] += x3 * wv.w;
    }

    float4 bv = {0.f, 0.f, 0.f, 0.f};
    if (bias) bv = *(const float4*)&bias[tx * 4];

#pragma unroll
    for (int i = 0; i < 4; ++i) {
        const int r = row0 + ty * 4 + i;
        if (r < N) {
            float4 o;
            o.x = acc[i][0] + bv.x; o.y = acc[i][1] + bv.y;
            o.z = acc[i][2] + bv.z; o.w = acc[i][3] + bv.w;
            if (RELU) {
                o.x = fmaxf(o.x, 0.f); o.y = fmaxf(o.y, 0.f);
                o.z = fmaxf(o.z, 0.f); o.w = fmaxf(o.w, 0.f);
            }
            *(float4*)&out[(size_t)r * 64 + tx * 4] = o;
        }
    }

    if (WANT_ALPHA) {
        const float4 asv = *(const float4*)&a_src[tx * 4];
        const float4 adv = *(const float4*)&a_dst[tx * 4];
#pragma unroll
        for (int i = 0; i < 4; ++i) {
            float s = acc[i][0]*asv.x + acc[i][1]*asv.y
                    + acc[i][2]*asv.z + acc[i][3]*asv.w;
            float d = acc[i][0]*adv.x + acc[i][1]*adv.y
                    + acc[i][2]*adv.z + acc[i][3]*adv.w;
#pragma unroll
            for (int off = 1; off < 16; off <<= 1) {
                s += __shfl_xor(s, off, 16);
                d += __shfl_xor(d, off, 16);
            }
            const int r = row0 + ty * 4 + i;
            if (tx == 0 && r < N) { alpha_s[r] = s; alpha_d[r] = d; }
        }
    }
}

// ---------------------------------------------------------------------------
// Final [N,64]x[64,32] projection.
// ---------------------------------------------------------------------------
template <int M>
__global__ __launch_bounds__(256) void gemm_small(
    const float* __restrict__ x, const float* __restrict__ W,
    const float* __restrict__ bias, float* __restrict__ out, int N)
{
    constexpr int RPB = 256 / M;
    __shared__ float Ws[64 * M];
    __shared__ float Xs[RPB][64];

    for (int i = threadIdx.x; i < 64 * M; i += 256) Ws[i] = W[i];
    const int row0 = blockIdx.x * RPB;
    for (int i = threadIdx.x; i < RPB * 64; i += 256) {
        int r = i >> 6, c = i & 63;
        Xs[r][c] = (row0 + r < N) ? x[(size_t)(row0 + r) * 64 + c] : 0.f;
    }
    __syncthreads();

    const int col = threadIdx.x % M;
    const int lr  = threadIdx.x / M;
    const int row = row0 + lr;

    float acc = 0.f;
#pragma unroll
    for (int k = 0; k < 64; ++k) acc += Xs[lr][k] * Ws[k * M + col];
    acc += bias[col];
    if (row < N) out[(size_t)row * M + col] = acc;
}

// ===========================================================================
// CSR build v2: 256-bucket histogram -> coarse partition -> in-bucket scatter
// (bucket b covers nodes [256b, 256b+256); requires N <= 65536)
// ===========================================================================
__global__ __launch_bounds__(256) void bucket_hist(
    const int* __restrict__ ei, int E, int* __restrict__ bhist)
{
    __shared__ int h[NBUCK];
    const int t = threadIdx.x;
    h[t] = 0;
    __syncthreads();
    for (int e = blockIdx.x * 256 + t; e < E; e += gridDim.x * 256)
        atomicAdd(&h[((unsigned)ei[E + e]) >> 8], 1);
    __syncthreads();
    if (h[t]) atomicAdd(&bhist[t], h[t]);
}

// Pass A: bin edges into buckets. Packed record: src | (local_node << 16).
// Bucket bases derived by in-block scan of bhist; gcurs holds RELATIVE
// cursors (zero-initialized).
#define PC_EPT 8
#define PC_TILE 2048
__global__ __launch_bounds__(256) void partition_coarse(
    const int* __restrict__ ei, int E, const int* __restrict__ bhist,
    int* __restrict__ gcurs, int* __restrict__ pairs)
{
    __shared__ int sc[NBUCK];
    __shared__ int hist[NBUCK];
    __shared__ int base[NBUCK];
    const int t = threadIdx.x;

    // exclusive scan of bhist -> bucket base offsets
    const int bh = bhist[t];
    sc[t] = bh; __syncthreads();
    for (int off = 1; off < 256; off <<= 1) {
        int v = sc[t];
        if (t >= off) v += sc[t - off];
        __syncthreads(); sc[t] = v; __syncthreads();
    }
    const int bbase = sc[t] - bh;
    hist[t] = 0;
    __syncthreads();

    const int tile0 = blockIdx.x * PC_TILE;
    int sv[PC_EPT], dv[PC_EPT], rk[PC_EPT];
#pragma unroll
    for (int i = 0; i < PC_EPT; ++i) {
        const int e = tile0 + i * 256 + t;
        if (e < E) {
            sv[i] = ei[e];
            dv[i] = ei[E + e];
            rk[i] = atomicAdd(&hist[dv[i] >> 8], 1);
        } else dv[i] = -1;
    }
    __syncthreads();
    if (hist[t] > 0) base[t] = bbase + atomicAdd(&gcurs[t], hist[t]);
    __syncthreads();
#pragma unroll
    for (int i = 0; i < PC_EPT; ++i) {
        if (dv[i] >= 0) {
            const int b = dv[i] >> 8;
            pairs[base[b] + rk[i]] = sv[i] | ((dv[i] & 255) << 16);
        }
    }
}

// Pass B: one block per bucket. Derives row_off for its 256 nodes (local
// hist + scan) and scatters its pairs segment into final CSR.
__global__ __launch_bounds__(256) void fine_scatter(
    const int* __restrict__ bhist, const int* __restrict__ pairs,
    int N, int E, int* __restrict__ row_off, int* __restrict__ csr_src)
{
    __shared__ int sc[NBUCK];
    __shared__ int cnt[NBUCK];
    __shared__ int cur[NBUCK];
    const int t = threadIdx.x, b = blockIdx.x;

    const int bh = bhist[t];
    sc[t] = bh; __syncthreads();
    for (int off = 1; off < 256; off <<= 1) {
        int v = sc[t];
        if (t >= off) v += sc[t - off];
        __syncthreads(); sc[t] = v; __syncthreads();
    }
    sc[t] -= bh;          // exclusive: bucket base
    cnt[t] = 0;
    __syncthreads();

    const int sb = sc[b];
    const int se = sb + bhist[b];

    for (int p = sb + t; p < se; p += 256)
        atomicAdd(&cnt[pairs[p] >> 16], 1);
    __syncthreads();

    // local exclusive scan of per-node counts
    const int c = cnt[t];
    cur[t] = c; __syncthreads();
    for (int off = 1; off < 256; off <<= 1) {
        int v = cur[t];
        if (t >= off) v += cur[t - off];
        __syncthreads(); cur[t] = v; __syncthreads();
    }
    const int node_off = sb + cur[t] - c;
    __syncthreads();
    cur[t] = node_off;
    const int n = b * 256 + t;
    if (n < N) row_off[n] = node_off;
    if (b == gridDim.x - 1 && t == 0) row_off[N] = E;
    __syncthreads();

    for (int p = sb + t; p < se; p += 256) {
        const int v = pairs[p];
        const int pos = atomicAdd(&cur[v >> 16], 1);
        csr_src[pos] = v & 0xFFFF;
    }
}

// ===========================================================================
// GAT aggregation v2, one wave per dst.
// Fast path (deg<=64): one edge per lane — lane-parallel ev, single wave
// max+sum reduction, ONE expf per edge, then 4-edge x 16-lane gather chunks
// with w/src pulled from registers via bpermute. Fallback: online softmax.
// ===========================================================================
__global__ __launch_bounds__(256) void gat_aggregate(
    const int* __restrict__ row_off, const int* __restrict__ csr_src,
    const float* __restrict__ h, const float* __restrict__ as,
    const float* __restrict__ ad, const float* __restrict__ bias,
    float* __restrict__ out, int N)
{
    const int wv = (blockIdx.x * 256 + threadIdx.x) >> 6;
    if (wv >= N) return;
    const int d    = wv;
    const int lane = threadIdx.x & 63;
    const int g    = lane >> 4;
    const int gl   = lane & 15;

    const int beg = row_off[d], end = row_off[d + 1];
    const int deg = end - beg;
    const float add = ad[d];

    float  den = 0.f;
    float4 acc = {0.f, 0.f, 0.f, 0.f};

    if (deg <= 64) {
        const bool v = lane < deg;
        const int  s = v ? csr_src[beg + lane] : 0;
        float ev = -FLT_BIG;
        if (v) {
            const float e0 = as[s] + add;
            ev = (e0 >= 0.f) ? e0 : NEG_SLOPE * e0;
        }
        float m = ev;
#pragma unroll
        for (int off = 1; off < 64; off <<= 1)
            m = fmaxf(m, __shfl_xor(m, off, 64));
        const float w = v ? __expf(ev - m) : 0.f;
        den = w;
#pragma unroll
        for (int off = 1; off < 64; off <<= 1)
            den += __shfl_xor(den, off, 64);

        for (int e0 = 0; e0 < deg; e0 += 4) {
            const int   idx = e0 + g;            // <= 63 whenever deg <= 64
            const int   sg  = __shfl(s, idx, 64);
            const float wg  = __shfl(w, idx, 64); // 0 for idx >= deg
            const float4 hv = *(const float4*)&h[(size_t)sg * 64 + gl * 4];
            acc.x += wg * hv.x; acc.y += wg * hv.y;
            acc.z += wg * hv.z; acc.w += wg * hv.w;
        }
    } else {
        // online-softmax fallback (rare)
        float m = -FLT_BIG;
        for (int e0 = beg; e0 < end; e0 += 4) {
            const int  e     = e0 + g;
            const bool valid = (e < end);
            const int  src   = valid ? csr_src[e] : 0;
            float ev = -FLT_BIG;
            if (valid) {
                const float vv = as[src] + add;
                ev = (vv >= 0.f) ? vv : NEG_SLOPE * vv;
            }
            float cm = ev;
            cm = fmaxf(cm, __shfl_xor(cm, 16, 64));
            cm = fmaxf(cm, __shfl_xor(cm, 32, 64));
            const float nm    = fmaxf(m, cm);
            const float scale = __expf(m - nm);
            acc.x *= scale; acc.y *= scale; acc.z *= scale; acc.w *= scale;
            den   *= scale;
            m = nm;
            const float w = valid ? __expf(ev - m) : 0.f;
            den += w;
            if (valid) {
                const float4 hv = *(const float4*)&h[(size_t)src * 64 + gl * 4];
                acc.x += w * hv.x; acc.y += w * hv.y;
                acc.z += w * hv.z; acc.w += w * hv.w;
            }
        }
        den += __shfl_xor(den, 16, 64);
        den += __shfl_xor(den, 32, 64);
    }

    // reduce the 4 edge-groups
#pragma unroll
    for (int off = 16; off <= 32; off <<= 1) {
        acc.x += __shfl_xor(acc.x, off, 64);
        acc.y += __shfl_xor(acc.y, off, 64);
        acc.z += __shfl_xor(acc.z, off, 64);
        acc.w += __shfl_xor(acc.w, off, 64);
    }

    if (g == 0) {
        const float4 bvv = *(const float4*)&bias[gl * 4];
        const float inv = (den > 0.f) ? (1.f / den) : 0.f;
        float4 o;
        o.x = fmaxf(acc.x * inv + bvv.x, 0.f);
        o.y = fmaxf(acc.y * inv + bvv.y, 0.f);
        o.z = fmaxf(acc.z * inv + bvv.z, 0.f);
        o.w = fmaxf(acc.w * inv + bvv.w, 0.f);
        *(float4*)&out[(size_t)d * 64 + gl * 4] = o;
    }
}

extern "C" void kernel_launch(void* const* d_in, const int* in_sizes, int n_in,
                              void* d_out, int out_size, void* d_ws, size_t ws_size,
                              hipStream_t stream)
{
    const float* x  = (const float*)d_in[0];
    const int*   ei = (const int*)d_in[1];
    const float* W[3]    = {(const float*)d_in[2], (const float*)d_in[6],  (const float*)d_in[10]};
    const float* asrc[3] = {(const float*)d_in[3], (const float*)d_in[7],  (const float*)d_in[11]};
    const float* adst[3] = {(const float*)d_in[4], (const float*)d_in[8],  (const float*)d_in[12]};
    const float* bia[3]  = {(const float*)d_in[5], (const float*)d_in[9],  (const float*)d_in[13]};
    const float* lin1W = (const float*)d_in[14];
    const float* lin1b = (const float*)d_in[15];
    const float* lin2W = (const float*)d_in[16];
    const float* lin2b = (const float*)d_in[17];

    const int N = in_sizes[0] / 64;
    const int E = in_sizes[1] / 2;
    const int B = (N + 255) / 256;            // coarse buckets (<=256)

    // workspace layout
    float* X       = (float*)d_ws;            // N*64
    float* H       = X + (size_t)N * 64;      // N*64 (aliased as pairs)
    float* AS      = H + (size_t)N * 64;      // N
    float* AD      = AS + N;                  // N
    int*   row_off = (int*)(AD + N);          // N+1
    int*   csr_src = row_off + (N + 1);       // E
    int*   bhist   = csr_src + E;             // 256
    int*   gcurs   = bhist + 256;             // 256
    int*   pairs   = (int*)H;                 // E ints (H dead until gemm)

    const int g64_grid = (N + 63) / 64;
    const int agg_grid = (N + 3) / 4;
    const int pc_grid  = (E + PC_TILE - 1) / PC_TILE;

    // ---- CSR build ----
    hipMemsetAsync(bhist, 0, 512 * sizeof(int), stream);
    bucket_hist<<<256, 256, 0, stream>>>(ei, E, bhist);
    partition_coarse<<<pc_grid, 256, 0, stream>>>(ei, E, bhist, gcurs, pairs);
    fine_scatter<<<B, 256, 0, stream>>>(bhist, pairs, N, E, row_off, csr_src);

    // ---- 3 GAT layers ----
    for (int l = 0; l < 3; ++l) {
        const float* in_act = (l == 0) ? x : X;
        gemm64<false, true><<<g64_grid, 256, 0, stream>>>(
            in_act, W[l], nullptr, asrc[l], adst[l], H, AS, AD, N);
        gat_aggregate<<<agg_grid, 256, 0, stream>>>(
            row_off, csr_src, H, AS, AD, bia[l], X, N);
    }

    // ---- MLP head ----
    gemm64<true, false><<<g64_grid, 256, 0, stream>>>(
        X, lin1W, lin1b, nullptr, nullptr, H, nullptr, nullptr, N);
    gemm_small<32><<<(N + 7) / 8, 256, 0, stream>>>(
        H, lin2W, lin2b, (float*)d_out, N);
}

// Round 5
// 227.080 us; speedup vs baseline: 4.3990x; 1.0753x over previous
//
#include <hip/hip_runtime.h>

#define NEG_SLOPE 0.2f
#define NBUCK 256

// ===========================================================================
// Register-blocked GEMM: out[N,64] = x[N,64] @ W[64,64] (+bias) (+relu)
// 64x64 tile per block; 256 threads; 4x4 outputs/thread.
// Optionally produces alpha_s/alpha_d = (out * a).sum(-1) via 16-lane reduce.
// ===========================================================================
template <bool RELU, bool WANT_ALPHA>
__global__ __launch_bounds__(256) void gemm64(
    const float* __restrict__ x, const float* __restrict__ W,
    const float* __restrict__ bias,
    const float* __restrict__ a_src, const float* __restrict__ a_dst,
    float* __restrict__ out, float* __restrict__ alpha_s,
    float* __restrict__ alpha_d, int N)
{
    __shared__ float Xs[64][68];   // +4 pad: column reads 2-way max (free)
    __shared__ float Ws[64][64];

    const int row0 = blockIdx.x * 64;

    for (int i = threadIdx.x; i < 1024; i += 256)
        ((float4*)Ws)[i] = ((const float4*)W)[i];
    for (int i = threadIdx.x; i < 1024; i += 256) {
        int r = i >> 4, c4 = (i & 15) * 4;
        float4 v = {0.f, 0.f, 0.f, 0.f};
        if (row0 + r < N) v = *(const float4*)&x[(size_t)(row0 + r) * 64 + c4];
        *(float4*)&Xs[r][c4] = v;
    }
    __syncthreads();

    const int tx = threadIdx.x & 15;
    const int ty = threadIdx.x >> 4;

    float acc[4][4] = {{0.f,0.f,0.f,0.f},{0.f,0.f,0.f,0.f},
                       {0.f,0.f,0.f,0.f},{0.f,0.f,0.f,0.f}};

#pragma unroll 8
    for (int k = 0; k < 64; ++k) {
        const float4 wv = *(const float4*)&Ws[k][tx * 4];
        const float x0 = Xs[ty * 4 + 0][k];
        const float x1 = Xs[ty * 4 + 1][k];
        const float x2 = Xs[ty * 4 + 2][k];
        const float x3 = Xs[ty * 4 + 3][k];
        acc[0][0] += x0 * wv.x; acc[0][1] += x0 * wv.y;
        acc[0][2] += x0 * wv.z; acc[0][3] += x0 * wv.w;
        acc[1][0] += x1 * wv.x; acc[1][1] += x1 * wv.y;
        acc[1][2] += x1 * wv.z; acc[1][3] += x1 * wv.w;
        acc[2][0] += x2 * wv.x; acc[2][1] += x2 * wv.y;
        acc[2][2] += x2 * wv.z; acc[2][3] += x2 * wv.w;
        acc[3][0] += x3 * wv.x; acc[3][1] += x3 * wv.y;
        acc[3][2] += x3 * wv.z; acc[3][3] += x3 * wv.w;
    }

    float4 bv = {0.f, 0.f, 0.f, 0.f};
    if (bias) bv = *(const float4*)&bias[tx * 4];

#pragma unroll
    for (int i = 0; i < 4; ++i) {
        const int r = row0 + ty * 4 + i;
        if (r < N) {
            float4 o;
            o.x = acc[i][0] + bv.x; o.y = acc[i][1] + bv.y;
            o.z = acc[i][2] + bv.z; o.w = acc[i][3] + bv.w;
            if (RELU) {
                o.x = fmaxf(o.x, 0.f); o.y = fmaxf(o.y, 0.f);
                o.z = fmaxf(o.z, 0.f); o.w = fmaxf(o.w, 0.f);
            }
            *(float4*)&out[(size_t)r * 64 + tx * 4] = o;
        }
    }

    if (WANT_ALPHA) {
        const float4 asv = *(const float4*)&a_src[tx * 4];
        const float4 adv = *(const float4*)&a_dst[tx * 4];
#pragma unroll
        for (int i = 0; i < 4; ++i) {
            float s = acc[i][0]*asv.x + acc[i][1]*asv.y
                    + acc[i][2]*asv.z + acc[i][3]*asv.w;
            float d = acc[i][0]*adv.x + acc[i][1]*adv.y
                    + acc[i][2]*adv.z + acc[i][3]*adv.w;
#pragma unroll
            for (int off = 1; off < 16; off <<= 1) {
                s += __shfl_xor(s, off, 16);
                d += __shfl_xor(d, off, 16);
            }
            const int r = row0 + ty * 4 + i;
            if (tx == 0 && r < N) { alpha_s[r] = s; alpha_d[r] = d; }
        }
    }
}

// ===========================================================================
// Fused MLP head: out[N,32] = relu(X @ W1 + b1) @ W2 + b2
// Phase 1 like gemm64 (into registers), T staged via Xs (reused), phase 2
// 64x32 GEMM, each thread 4 rows x 2 cols.
// ===========================================================================
__global__ __launch_bounds__(256) void gemm_head(
    const float* __restrict__ X, const float* __restrict__ W1,
    const float* __restrict__ b1, const float* __restrict__ W2,
    const float* __restrict__ b2, float* __restrict__ out, int N)
{
    __shared__ float Xs[64][68];
    __shared__ float W1s[64][64];
    __shared__ float W2s[64][32];

    const int row0 = blockIdx.x * 64;

    for (int i = threadIdx.x; i < 1024; i += 256)
        ((float4*)W1s)[i] = ((const float4*)W1)[i];
    for (int i = threadIdx.x; i < 512; i += 256)
        ((float4*)W2s)[i] = ((const float4*)W2)[i];
    for (int i = threadIdx.x; i < 1024; i += 256) {
        int r = i >> 4, c4 = (i & 15) * 4;
        float4 v = {0.f, 0.f, 0.f, 0.f};
        if (row0 + r < N) v = *(const float4*)&X[(size_t)(row0 + r) * 64 + c4];
        *(float4*)&Xs[r][c4] = v;
    }
    __syncthreads();

    const int tx = threadIdx.x & 15;
    const int ty = threadIdx.x >> 4;

    float acc[4][4] = {{0.f,0.f,0.f,0.f},{0.f,0.f,0.f,0.f},
                       {0.f,0.f,0.f,0.f},{0.f,0.f,0.f,0.f}};
#pragma unroll 8
    for (int k = 0; k < 64; ++k) {
        const float4 wv = *(const float4*)&W1s[k][tx * 4];
        const float x0 = Xs[ty * 4 + 0][k];
        const float x1 = Xs[ty * 4 + 1][k];
        const float x2 = Xs[ty * 4 + 2][k];
        const float x3 = Xs[ty * 4 + 3][k];
        acc[0][0] += x0 * wv.x; acc[0][1] += x0 * wv.y;
        acc[0][2] += x0 * wv.z; acc[0][3] += x0 * wv.w;
        acc[1][0] += x1 * wv.x; acc[1][1] += x1 * wv.y;
        acc[1][2] += x1 * wv.z; acc[1][3] += x1 * wv.w;
        acc[2][0] += x2 * wv.x; acc[2][1] += x2 * wv.y;
        acc[2][2] += x2 * wv.z; acc[2][3] += x2 * wv.w;
        acc[3][0] += x3 * wv.x; acc[3][1] += x3 * wv.y;
        acc[3][2] += x3 * wv.z; acc[3][3] += x3 * wv.w;
    }

    const float4 bv = *(const float4*)&b1[tx * 4];
    __syncthreads();   // done reading Xs as X
#pragma unroll
    for (int i = 0; i < 4; ++i) {
        Xs[ty * 4 + i][tx * 4 + 0] = fmaxf(acc[i][0] + bv.x, 0.f);
        Xs[ty * 4 + i][tx * 4 + 1] = fmaxf(acc[i][1] + bv.y, 0.f);
        Xs[ty * 4 + i][tx * 4 + 2] = fmaxf(acc[i][2] + bv.z, 0.f);
        Xs[ty * 4 + i][tx * 4 + 3] = fmaxf(acc[i][3] + bv.w, 0.f);
    }
    __syncthreads();

    // phase 2: T[64,64] @ W2[64,32]; each thread 4 rows x 2 cols
    float a2[4][2] = {{0.f,0.f},{0.f,0.f},{0.f,0.f},{0.f,0.f}};
#pragma unroll 8
    for (int k = 0; k < 64; ++k) {
        const float2 wv = *(const float2*)&W2s[k][tx * 2];
        const float t0 = Xs[ty * 4 + 0][k];
        const float t1 = Xs[ty * 4 + 1][k];
        const float t2 = Xs[ty * 4 + 2][k];
        const float t3 = Xs[ty * 4 + 3][k];
        a2[0][0] += t0 * wv.x; a2[0][1] += t0 * wv.y;
        a2[1][0] += t1 * wv.x; a2[1][1] += t1 * wv.y;
        a2[2][0] += t2 * wv.x; a2[2][1] += t2 * wv.y;
        a2[3][0] += t3 * wv.x; a2[3][1] += t3 * wv.y;
    }
    const float2 b2v = *(const float2*)&b2[tx * 2];
#pragma unroll
    for (int i = 0; i < 4; ++i) {
        const int r = row0 + ty * 4 + i;
        if (r < N) {
            float2 o;
            o.x = a2[i][0] + b2v.x;
            o.y = a2[i][1] + b2v.y;
            *(float2*)&out[(size_t)r * 32 + tx * 2] = o;
        }
    }
}

// ===========================================================================
// CSR build: 256-bucket histogram -> coarse partition -> in-bucket scatter
// ===========================================================================
__global__ __launch_bounds__(256) void bucket_hist(
    const int* __restrict__ ei, int E, int* __restrict__ bhist)
{
    __shared__ int h[NBUCK];
    const int t = threadIdx.x;
    h[t] = 0;
    __syncthreads();
    for (int e = blockIdx.x * 256 + t; e < E; e += gridDim.x * 256)
        atomicAdd(&h[((unsigned)ei[E + e]) >> 8], 1);
    __syncthreads();
    if (h[t]) atomicAdd(&bhist[t], h[t]);
}

#define PC_EPT 8
#define PC_TILE 2048
__global__ __launch_bounds__(256) void partition_coarse(
    const int* __restrict__ ei, int E, const int* __restrict__ bhist,
    int* __restrict__ gcurs, int* __restrict__ pairs)
{
    __shared__ int sc[NBUCK];
    __shared__ int hist[NBUCK];
    __shared__ int base[NBUCK];
    const int t = threadIdx.x;

    const int bh = bhist[t];
    sc[t] = bh; __syncthreads();
    for (int off = 1; off < 256; off <<= 1) {
        int v = sc[t];
        if (t >= off) v += sc[t - off];
        __syncthreads(); sc[t] = v; __syncthreads();
    }
    const int bbase = sc[t] - bh;
    hist[t] = 0;
    __syncthreads();

    const int tile0 = blockIdx.x * PC_TILE;
    int sv[PC_EPT], dv[PC_EPT], rk[PC_EPT];
#pragma unroll
    for (int i = 0; i < PC_EPT; ++i) {
        const int e = tile0 + i * 256 + t;
        if (e < E) {
            sv[i] = ei[e];
            dv[i] = ei[E + e];
            rk[i] = atomicAdd(&hist[dv[i] >> 8], 1);
        } else dv[i] = -1;
    }
    __syncthreads();
    if (hist[t] > 0) base[t] = bbase + atomicAdd(&gcurs[t], hist[t]);
    __syncthreads();
#pragma unroll
    for (int i = 0; i < PC_EPT; ++i) {
        if (dv[i] >= 0) {
            const int b = dv[i] >> 8;
            pairs[base[b] + rk[i]] = sv[i] | ((dv[i] & 255) << 16);
        }
    }
}

__global__ __launch_bounds__(256) void fine_scatter(
    const int* __restrict__ bhist, const int* __restrict__ pairs,
    int N, int E, int* __restrict__ row_off, int* __restrict__ csr_src)
{
    __shared__ int sc[NBUCK];
    __shared__ int cnt[NBUCK];
    __shared__ int cur[NBUCK];
    const int t = threadIdx.x, b = blockIdx.x;

    const int bh = bhist[t];
    sc[t] = bh; __syncthreads();
    for (int off = 1; off < 256; off <<= 1) {
        int v = sc[t];
        if (t >= off) v += sc[t - off];
        __syncthreads(); sc[t] = v; __syncthreads();
    }
    sc[t] -= bh;
    cnt[t] = 0;
    __syncthreads();

    const int sb = sc[b];
    const int se = sb + bhist[b];

    for (int p = sb + t; p < se; p += 256)
        atomicAdd(&cnt[pairs[p] >> 16], 1);
    __syncthreads();

    const int c = cnt[t];
    cur[t] = c; __syncthreads();
    for (int off = 1; off < 256; off <<= 1) {
        int v = cur[t];
        if (t >= off) v += cur[t - off];
        __syncthreads(); cur[t] = v; __syncthreads();
    }
    const int node_off = sb + cur[t] - c;
    __syncthreads();
    cur[t] = node_off;
    const int n = b * 256 + t;
    if (n < N) row_off[n] = node_off;
    if (b == gridDim.x - 1 && t == 0) row_off[N] = E;
    __syncthreads();

    for (int p = sb + t; p < se; p += 256) {
        const int v = pairs[p];
        const int pos = atomicAdd(&cur[v >> 16], 1);
        csr_src[pos] = v & 0xFFFF;
    }
}

// ===========================================================================
// GAT aggregation v3, one wave per dst. Softmax WITHOUT max-shift (exact to
// fp32 rounding: shift-invariance; |e| << 88 so exp(e) cannot overflow).
// Pure gather-FMA loop: 4 edge-groups x 16 lanes, zero cross-lane ops in the
// loop; single 2-shuffle reduce at the end. Handles any degree uniformly.
// ===========================================================================
__global__ __launch_bounds__(256) void gat_aggregate(
    const int* __restrict__ row_off, const int* __restrict__ csr_src,
    const float* __restrict__ h, const float* __restrict__ as,
    const float* __restrict__ ad, const float* __restrict__ bias,
    float* __restrict__ out, int N)
{
    const int wv = (blockIdx.x * 256 + threadIdx.x) >> 6;
    if (wv >= N) return;
    const int d    = wv;
    const int lane = threadIdx.x & 63;
    const int g    = lane >> 4;
    const int gl   = lane & 15;

    const int beg = row_off[d], end = row_off[d + 1];
    const float add = ad[d];

    float  den = 0.f;
    float4 acc = {0.f, 0.f, 0.f, 0.f};

    // software pipeline: src index one chunk ahead
    int srcp = (beg + g < end) ? csr_src[beg + g] : 0;

    for (int e0 = beg; e0 < end; e0 += 4) {
        const bool valid = (e0 + g < end);
        const int  s     = srcp;
        const int  en    = e0 + 4 + g;
        srcp = (en < end) ? csr_src[en] : 0;

        const float av = as[s];                               // group broadcast
        const float4 hv = *(const float4*)&h[(size_t)s * 64 + gl * 4];

        float ev = av + add;
        ev = (ev >= 0.f) ? ev : NEG_SLOPE * ev;
        const float w = valid ? __expf(ev) : 0.f;

        den += w;
        acc.x += w * hv.x; acc.y += w * hv.y;
        acc.z += w * hv.z; acc.w += w * hv.w;
    }

    // reduce the 4 edge-groups (lanes differ in bits 4,5)
#pragma unroll
    for (int off = 16; off <= 32; off <<= 1) {
        acc.x += __shfl_xor(acc.x, off, 64);
        acc.y += __shfl_xor(acc.y, off, 64);
        acc.z += __shfl_xor(acc.z, off, 64);
        acc.w += __shfl_xor(acc.w, off, 64);
        den   += __shfl_xor(den,   off, 64);
    }

    if (g == 0) {
        const float4 bvv = *(const float4*)&bias[gl * 4];
        const float inv = (den > 0.f) ? (1.f / den) : 0.f;
        float4 o;
        o.x = fmaxf(acc.x * inv + bvv.x, 0.f);
        o.y = fmaxf(acc.y * inv + bvv.y, 0.f);
        o.z = fmaxf(acc.z * inv + bvv.z, 0.f);
        o.w = fmaxf(acc.w * inv + bvv.w, 0.f);
        *(float4*)&out[(size_t)d * 64 + gl * 4] = o;
    }
}

extern "C" void kernel_launch(void* const* d_in, const int* in_sizes, int n_in,
                              void* d_out, int out_size, void* d_ws, size_t ws_size,
                              hipStream_t stream)
{
    const float* x  = (const float*)d_in[0];
    const int*   ei = (const int*)d_in[1];
    const float* W[3]    = {(const float*)d_in[2], (const float*)d_in[6],  (const float*)d_in[10]};
    const float* asrc[3] = {(const float*)d_in[3], (const float*)d_in[7],  (const float*)d_in[11]};
    const float* adst[3] = {(const float*)d_in[4], (const float*)d_in[8],  (const float*)d_in[12]};
    const float* bia[3]  = {(const float*)d_in[5], (const float*)d_in[9],  (const float*)d_in[13]};
    const float* lin1W = (const float*)d_in[14];
    const float* lin1b = (const float*)d_in[15];
    const float* lin2W = (const float*)d_in[16];
    const float* lin2b = (const float*)d_in[17];

    const int N = in_sizes[0] / 64;
    const int E = in_sizes[1] / 2;
    const int B = (N + 255) / 256;            // coarse buckets (<=256)

    // workspace layout
    float* X       = (float*)d_ws;            // N*64
    float* H       = X + (size_t)N * 64;      // N*64 (aliased as pairs)
    float* AS      = H + (size_t)N * 64;      // N
    float* AD      = AS + N;                  // N
    int*   row_off = (int*)(AD + N);          // N+1
    int*   csr_src = row_off + (N + 1);       // E
    int*   bhist   = csr_src + E;             // 256
    int*   gcurs   = bhist + 256;             // 256
    int*   pairs   = (int*)H;                 // E ints (H dead until gemm)

    const int g64_grid = (N + 63) / 64;
    const int agg_grid = (N + 3) / 4;
    const int pc_grid  = (E + PC_TILE - 1) / PC_TILE;

    // ---- CSR build ----
    hipMemsetAsync(bhist, 0, 512 * sizeof(int), stream);
    bucket_hist<<<256, 256, 0, stream>>>(ei, E, bhist);
    partition_coarse<<<pc_grid, 256, 0, stream>>>(ei, E, bhist, gcurs, pairs);
    fine_scatter<<<B, 256, 0, stream>>>(bhist, pairs, N, E, row_off, csr_src);

    // ---- 3 GAT layers ----
    for (int l = 0; l < 3; ++l) {
        const float* in_act = (l == 0) ? x : X;
        gemm64<false, true><<<g64_grid, 256, 0, stream>>>(
            in_act, W[l], nullptr, asrc[l], adst[l], H, AS, AD, N);
        gat_aggregate<<<agg_grid, 256, 0, stream>>>(
            row_off, csr_src, H, AS, AD, bia[l], X, N);
    }

    // ---- fused MLP head ----
    gemm_head<<<g64_grid, 256, 0, stream>>>(
        X, lin1W, lin1b, lin2W, lin2b, (float*)d_out, N);
}